// Round 11
// baseline (235.490 us; speedup 1.0000x reference)
//
#include <hip/hip_runtime.h>
#include <hip/hip_bf16.h>

// ---------------------------------------------------------------------------
// Fused GQA attention block for B=2,T=2048,D=1024,N=16,K=8,H=128 on gfx950.
// R11: flash -> mfma 32x32x16 (2x FLOP per LDS fragment read; flash was
//      ~55% LDS-pipe-bound). Wave = 32 Q rows x (S-subtile/H-half); P slab
//      per row-half assembled by sibling waves (+1 barrier). l via dup
//      ones-MFMA. gemm_out -> BK=128 (half the barriers; grid-capped
//      occupancy unaffected). gemm_qkv/prep unchanged from R10.
// ---------------------------------------------------------------------------

typedef unsigned short u16;
typedef __attribute__((ext_vector_type(8))) short s16x8;    // 8 bf16 (MFMA A/B frag)
typedef __attribute__((ext_vector_type(4))) float fp32x4;   // 16x16 C/D frag
typedef __attribute__((ext_vector_type(16))) float fp32x16; // 32x32 C/D frag
typedef __attribute__((ext_vector_type(4))) u16 u16x4;

#define MFMA_BF16(a, b, c) __builtin_amdgcn_mfma_f32_16x16x32_bf16((a), (b), (c), 0, 0, 0)
#define MFMA32(a, b, c) __builtin_amdgcn_mfma_f32_32x32x16_bf16((a), (b), (c), 0, 0, 0)

static constexpr int Bq = 2, Tq = 2048, Dq = 1024, NHq = 16, KHq = 8, Hq = 128;
static constexpr float EPSq = 1e-6f;
static constexpr float S2q = 0.08838834764831845f * 1.4426950408889634f;
static constexpr float MAXq = 20.0f;   // static softmax max (exp2 domain)
static constexpr float NEGHUGE = -3.0e38f;

__device__ __forceinline__ u16 f2b(float f) {
  __hip_bfloat16 h = __float2bfloat16(f);
  return *reinterpret_cast<u16*>(&h);
}

__device__ __forceinline__ void gload16(const u16* g, u16* lds_base) {
  __builtin_amdgcn_global_load_lds(
      (const __attribute__((address_space(1))) unsigned int*)(const void*)g,
      (__attribute__((address_space(3))) unsigned int*)(void*)lds_base, 16, 0, 0);
}

// ---------------- merged prep kernel (unchanged) ----------------------------

__global__ __launch_bounds__(256) void prep_kernel(
    const float* __restrict__ x, const float* __restrict__ wq,
    const float* __restrict__ wk, const float* __restrict__ wv,
    const float* __restrict__ wo, const int* __restrict__ seg,
    u16* __restrict__ xb, u16* __restrict__ wqkv_t, u16* __restrict__ wo_t,
    int* __restrict__ pos) {
  const int bid = blockIdx.x;
  const int tid = threadIdx.x;
  if (bid < 4096) {
    const int i = bid * 1024 + tid * 4;
    const float4 v = *reinterpret_cast<const float4*>(x + i);
    u16x4 o;
    o.x = f2b(v.x); o.y = f2b(v.y); o.z = f2b(v.z); o.w = f2b(v.w);
    *reinterpret_cast<u16x4*>(xb + i) = o;
    return;
  }
  __shared__ float tile[32][33];
  __shared__ int sv[256], si[256];
  const int tx = tid & 31, ty = tid >> 5;
  if (bid < 8192) {
    const int z = bid - 4096;
    const int r0 = (z & 31) * 32;
    const int c0 = (z >> 5) * 32;
    const float* src;
    int stride, coff;
    if (c0 < 2048)      { src = wq; stride = 2048; coff = c0; }
    else if (c0 < 3072) { src = wk; stride = 1024; coff = c0 - 2048; }
    else                { src = wv; stride = 1024; coff = c0 - 3072; }
#pragma unroll
    for (int j = 0; j < 32; j += 8)
      tile[ty + j][tx] = src[(long)(r0 + ty + j) * stride + (coff + tx)];
    __syncthreads();
#pragma unroll
    for (int j = 0; j < 32; j += 8)
      wqkv_t[(long)(c0 + ty + j) * 1024 + (r0 + tx)] = f2b(tile[tx][ty + j]);
    return;
  }
  if (bid < 10240) {
    const int z = bid - 8192;
    const int c0 = (z & 31) * 32;
    const int r0 = (z >> 5) * 32;
#pragma unroll
    for (int j = 0; j < 32; j += 8)
      tile[ty + j][tx] = wo[(long)(r0 + ty + j) * 1024 + (c0 + tx)];
    __syncthreads();
#pragma unroll
    for (int j = 0; j < 32; j += 8)
      wo_t[(long)(c0 + ty + j) * 2048 + (r0 + tx)] = f2b(tile[tx][ty + j]);
    return;
  }
  const int b = bid - 10240;
  const int* s = seg + b * Tq;
  int bestv = -2147483647 - 1, besti = 0x7fffffff;
  for (int t = tid; t < Tq; t += 256) {
    int v = s[t];
    if (v > bestv) { bestv = v; besti = t; }
  }
  sv[tid] = bestv; si[tid] = besti;
  __syncthreads();
  for (int k = 128; k > 0; k >>= 1) {
    if (tid < k) {
      int v2 = sv[tid + k], i2 = si[tid + k];
      if (v2 > sv[tid] || (v2 == sv[tid] && i2 < si[tid])) {
        sv[tid] = v2; si[tid] = i2;
      }
    }
    __syncthreads();
  }
  const int off = si[0];
  for (int t = tid; t < Tq; t += 256)
    pos[b * Tq + t] = (s[t] != 0) ? (t - off) : (1 << 30);
}

// ---------------- QKV GEMM + fused norm/rope/v-transpose (unchanged) --------

__global__ __launch_bounds__(256) void gemm_qkv_kernel(
    const u16* __restrict__ A, const u16* __restrict__ Bt,
    u16* __restrict__ qkv, u16* __restrict__ vt, const int* __restrict__ pos,
    const float* __restrict__ q_scale, const float* __restrict__ k_scale) {
  __shared__ __align__(16) u16 As[128][64];
  __shared__ __align__(16) u16 Bs[128][64];
  const int tid = threadIdx.x;
  const int wave = tid >> 6, lane = tid & 63;
  const int quad = lane >> 4, l16 = lane & 15;
  const int m0 = blockIdx.y * 128, n0 = blockIdx.x * 128;
  const int row8 = lane >> 3;
  const int cgl = (lane & 7) ^ row8;

  const fp32x4 z4 = {0.f, 0.f, 0.f, 0.f};
  fp32x4 acc[2][8];
#pragma unroll
  for (int i = 0; i < 2; ++i)
#pragma unroll
    for (int j = 0; j < 8; ++j) acc[i][j] = z4;

  for (int k0 = 0; k0 < 1024; k0 += 64) {
    __syncthreads();
#pragma unroll
    for (int jj = 0; jj < 4; ++jj) {
      const int R = wave * 32 + jj * 8;
      gload16(A + (size_t)(m0 + R + row8) * 1024 + k0 + cgl * 8, &As[R][0]);
      gload16(Bt + (size_t)(n0 + R + row8) * 1024 + k0 + cgl * 8, &Bs[R][0]);
    }
    __syncthreads();
#pragma unroll
    for (int kh = 0; kh < 2; ++kh) {
      s16x8 af[2], bfr[8];
#pragma unroll
      for (int i = 0; i < 2; ++i)
        af[i] = *(const s16x8*)&As[wave * 32 + i * 16 + l16]
                               [((((kh << 2) | quad) ^ (l16 & 7)) << 3)];
#pragma unroll
      for (int j = 0; j < 8; ++j)
        bfr[j] = *(const s16x8*)&Bs[j * 16 + l16]
                                [((((kh << 2) | quad) ^ (l16 & 7)) << 3)];
#pragma unroll
      for (int i = 0; i < 2; ++i)
#pragma unroll
        for (int j = 0; j < 8; ++j) acc[i][j] = MFMA_BF16(af[i], bfr[j], acc[i][j]);
    }
  }

  const int wrow = m0 + wave * 32;
  if (n0 >= 3072) {
    const int kv8 = (n0 - 3072) >> 7;
    const int bq = wrow >> 11;
    const size_t vbase = (size_t)(bq * KHq + kv8) * Hq * Tq;
#pragma unroll
    for (int i = 0; i < 2; ++i) {
      const int t = (wrow + i * 16 + quad * 4) & 2047;
#pragma unroll
      for (int j = 0; j < 8; ++j) {
        const int h = j * 16 + l16;
        u16x4 o;
#pragma unroll
        for (int r = 0; r < 4; ++r) o[r] = f2b(acc[i][j][r]);
        *reinterpret_cast<u16x4*>(&vt[vbase + (size_t)h * Tq + t]) = o;
      }
    }
    return;
  }
  const float* scp = (n0 < 2048) ? q_scale : k_scale;
  float scl[8];
#pragma unroll
  for (int j = 0; j < 8; ++j) scl[j] = scp[j * 16 + l16];
  float invf[4];
#pragma unroll
  for (int jf = 0; jf < 4; ++jf)
    invf[jf] = __builtin_amdgcn_exp2f(
                   -(float)(jf * 16 + l16) * (19.931568569324174f / 64.0f)) *
               0.15915494309189535f;
#pragma unroll
  for (int i = 0; i < 2; ++i) {
    float ss[4] = {0.f, 0.f, 0.f, 0.f};
#pragma unroll
    for (int j = 0; j < 8; ++j)
#pragma unroll
      for (int r = 0; r < 4; ++r) ss[r] += acc[i][j][r] * acc[i][j][r];
#pragma unroll
    for (int d = 1; d < 16; d <<= 1)
#pragma unroll
      for (int r = 0; r < 4; ++r) ss[r] += __shfl_xor(ss[r], d, 64);
#pragma unroll
    for (int r = 0; r < 4; ++r) {
      const int row = wrow + i * 16 + quad * 4 + r;
      const float rinv = rsqrtf(ss[r] * (1.0f / 128.0f) + EPSq);
      const float P = (float)pos[row];
      u16* orow = qkv + (size_t)row * 4096 + n0;
#pragma unroll
      for (int jf = 0; jf < 4; ++jf) {
        float rev = P * invf[jf];
        rev -= floorf(rev);
        const float s = __builtin_amdgcn_sinf(rev);
        const float c = __builtin_amdgcn_cosf(rev);
        const float a1 = acc[i][jf][r] * rinv * scl[jf];
        const float a2 = acc[i][jf + 4][r] * rinv * scl[jf + 4];
        orow[jf * 16 + l16] = f2b(a1 * c - a2 * s);
        orow[(jf + 4) * 16 + l16] = f2b(a2 * c + a1 * s);
      }
    }
  }
}

// ---------------- out-proj GEMM: BK=128 -------------------------------------
// 128x64 tile, K=2048 in 16 iterations (half the barriers of BK=64). LDS rows
// are 256B = 16 chunks; XOR swizzle chunk^(row&15). Grid 512 = 2 blocks/CU
// (grid-capped, so 48KB LDS costs no occupancy).

__global__ __launch_bounds__(256) void gemm_out_kernel(
    const u16* __restrict__ A, const u16* __restrict__ Bt,
    float* __restrict__ C) {
  __shared__ __align__(16) u16 As[128][128];
  __shared__ __align__(16) u16 Bs[64][128];
  const int tid = threadIdx.x;
  const int wave = tid >> 6, lane = tid & 63;
  const int quad = lane >> 4, l16 = lane & 15;
  const int m0 = blockIdx.y * 128, n0 = blockIdx.x * 64;
  const int wm = (wave >> 1) * 64, wn = (wave & 1) * 32;
  const int row4 = lane >> 4;          // 0..3 within a 4-row issue (256B rows)
  const int cgl16 = lane & 15;         // 16B chunk index before swizzle

  const fp32x4 z4 = {0.f, 0.f, 0.f, 0.f};
  fp32x4 acc[4][2];
#pragma unroll
  for (int i = 0; i < 4; ++i)
#pragma unroll
    for (int j = 0; j < 2; ++j) acc[i][j] = z4;

  for (int k0 = 0; k0 < 2048; k0 += 128) {
    __syncthreads();
#pragma unroll
    for (int jj = 0; jj < 8; ++jj) {    // A: 32 rows per wave, 4 rows/issue
      const int R = wave * 32 + jj * 4;
      const int r = R + row4;
      const int cg = cgl16 ^ (r & 15);
      gload16(A + (size_t)(m0 + r) * 2048 + k0 + cg * 8, &As[R][0]);
    }
#pragma unroll
    for (int jj = 0; jj < 4; ++jj) {    // B: 16 rows per wave
      const int R = wave * 16 + jj * 4;
      const int r = R + row4;
      const int cg = cgl16 ^ (r & 15);
      gload16(Bt + (size_t)(n0 + r) * 2048 + k0 + cg * 8, &Bs[R][0]);
    }
    __syncthreads();
#pragma unroll
    for (int kh = 0; kh < 4; ++kh) {
      s16x8 af[4], bfr[2];
#pragma unroll
      for (int i = 0; i < 4; ++i) {
        const int r = wm + i * 16 + l16;
        af[i] = *(const s16x8*)&As[r][((((kh << 2) | quad) ^ (r & 15)) << 3)];
      }
#pragma unroll
      for (int j = 0; j < 2; ++j) {
        const int r = wn + j * 16 + l16;
        bfr[j] = *(const s16x8*)&Bs[r][((((kh << 2) | quad) ^ (r & 15)) << 3)];
      }
#pragma unroll
      for (int i = 0; i < 4; ++i)
#pragma unroll
        for (int j = 0; j < 2; ++j) acc[i][j] = MFMA_BF16(af[i], bfr[j], acc[i][j]);
    }
  }
#pragma unroll
  for (int i = 0; i < 4; ++i) {
    const int row = m0 + wm + i * 16 + quad * 4;
#pragma unroll
    for (int j = 0; j < 2; ++j) {
      const int col = n0 + wn + j * 16 + l16;
#pragma unroll
      for (int r = 0; r < 4; ++r)
        C[(size_t)(row + r) * 1024 + col] = acc[i][j][r];
    }
  }
}

// ---------------- flash attention: 32x32x16 MFMA ----------------------------
// Block = (b, kv, qh, p): phases {31-p, p} (33 S-tile iters uniform).
// Wave w: Q rows rh=w&1 (32 rows of the 64-row chunk), sh=w>>1 selects the
// S-subtile (QK) and H-half (PV). P slab per row-half is assembled by the
// sibling waves (sh=0 writes S 0-31, sh=1 writes S 32-63) -> barrier #3.
// l via ones-MFMA (duplicated per wave). C/D map (verified m74/m101):
// col=lane&31, row=(reg&3)+8*(reg>>2)+4*(lane>>5). A/B frag: m|n=lane&31,
// k=(lane>>5)*8+j. Static-max softmax; dense-single-segment tile iteration.

__global__ __launch_bounds__(256, 2) void flash_kernel(
    const u16* __restrict__ qkv, const u16* __restrict__ vt,
    const int* __restrict__ pos, const int* __restrict__ seg,
    u16* __restrict__ Obuf) {
  const int tid = threadIdx.x;
  const int w = tid >> 6;
  const int lane = tid & 63;
  const int l32 = lane & 31;
  const int lh = lane >> 5;            // lane half -> k-chunk in A/B frags
  const int rh = w & 1;                // row-half of the 64-row chunk
  const int sh = w >> 1;               // S-subtile (QK) / H-half (PV)
  const int g = blockIdx.x;
  const int b = g & 1;
  const int kv = (g >> 1) & 7;
  const int qh = kv * 2 + ((g >> 4) & 1);
  const int p = g >> 5;                // 0..15

  __shared__ __align__(16) u16 Ks[64][128];   // [s][h], chunk-swizzled
  __shared__ __align__(16) u16 Vs[128][64];   // [h][s], chunk-swizzled
  __shared__ __align__(16) u16 Ps[2][32][76]; // per row-half P slab (+pad)

  const u16* kbase = qkv + (size_t)(b * Tq) * 4096 + 2048 + kv * Hq;
  const u16* vbase = vt + (size_t)(b * KHq + kv) * Hq * Tq;
  const int krow_off = lane >> 4;
  const int vrow_off = lane >> 3;
  const short one_bf = (short)0x3F80;
  const s16x8 ones = {one_bf, one_bf, one_bf, one_bf,
                      one_bf, one_bf, one_bf, one_bf};

#pragma unroll
  for (int phase = 0; phase < 2; ++phase) {
    const int c = phase ? p : 31 - p;
    const int t0 = c * 64 + rh * 32;    // this wave's 32 Q rows
    const int nst = c + 1;

    // Q A-frags: 8 k-steps of 16 over H=128
    s16x8 qf[8];
    {
      const u16* qrow = qkv + (size_t)(b * Tq + t0 + l32) * 4096 + qh * Hq;
#pragma unroll
      for (int ks = 0; ks < 8; ++ks)
        qf[ks] = *(const s16x8*)(qrow + ks * 16 + lh * 8);
    }
    int myp[16], mys[16];
#pragma unroll
    for (int r = 0; r < 16; ++r) {
      const int t = t0 + 4 * lh + (r & 3) + 8 * (r >> 2);
      myp[r] = pos[b * Tq + t];
      mys[r] = seg[b * Tq + t];
    }
    fp32x16 l_acc = {};
    fp32x16 o_acc[2] = {};

    for (int st = 0; st < nst; ++st) {
      const int s0 = st * 64;
      __syncthreads();  // prior iter's Ks/Vs reads complete
#pragma unroll
      for (int j = 0; j < 4; ++j) {     // stage K rows w*16..+16
        const int R = w * 16 + j * 4;
        const int r = R + krow_off;
        const int cg = (lane & 15) ^ (r & 15);
        gload16(kbase + (size_t)(s0 + r) * 4096 + cg * 8, &Ks[R][0]);
      }
#pragma unroll
      for (int j = 0; j < 4; ++j) {     // stage V^T rows w*32..+32
        const int R = w * 32 + j * 8;
        const int r = R + vrow_off;
        const int cg = (lane & 7) ^ (vrow_off & 7);
        gload16(vbase + (size_t)r * Tq + s0 + cg * 8, &Vs[R][0]);
      }
      __syncthreads();  // tiles visible (vmcnt drained at barrier)

      // ---- QK^T: 32 Q rows x 32 S cols (subtile sh), 8 MFMA ----
      fp32x16 sc = {};
      const int srow = sh * 32 + l32;
#pragma unroll
      for (int ks = 0; ks < 8; ++ks) {
        const s16x8 kf =
            *(const s16x8*)&Ks[srow][((((ks << 1) | lh) ^ (l32 & 15)) << 3)];
        sc = MFMA32(qf[ks], kf, sc);
      }

      // ---- mask + static-max exp2 ----
      const int scol = s0 + sh * 32 + l32;
      const int spos = pos[b * Tq + scol];
      const int sseg = seg[b * Tq + scol];
      if (st == nst - 1) {
#pragma unroll
        for (int r = 0; r < 16; ++r) {
          const bool ok = (sseg == mys[r]) && (spos <= myp[r]);
          sc[r] = ok ? sc[r] * S2q - MAXq : NEGHUGE;
        }
      } else {
#pragma unroll
        for (int r = 0; r < 16; ++r) sc[r] = sc[r] * S2q - MAXq;
      }
      // ---- P -> slab (sibling waves fill the two S-halves) ----
#pragma unroll
      for (int r = 0; r < 16; ++r)
        Ps[rh][4 * lh + (r & 3) + 8 * (r >> 2)][sh * 32 + l32] =
            f2b(__builtin_amdgcn_exp2f(sc[r]));
      __syncthreads();  // cross-wave P exchange

      // ---- P A-frags over full S=64 (4 k-steps) ----
      s16x8 pf[4];
#pragma unroll
      for (int ks = 0; ks < 4; ++ks)
        pf[ks] = *(const s16x8*)&Ps[rh][l32][ks * 16 + lh * 8];
      // ---- l += P*1 (4 MFMA, dup per wave) ----
#pragma unroll
      for (int ks = 0; ks < 4; ++ks) l_acc = MFMA32(pf[ks], ones, l_acc);
      // ---- O += P*V over this wave's H-half (2 n-tiles x 4 k) ----
#pragma unroll
      for (int nt = 0; nt < 2; ++nt) {
        const int vrow = sh * 64 + nt * 32 + l32;
#pragma unroll
        for (int ks = 0; ks < 4; ++ks) {
          const s16x8 vf =
              *(const s16x8*)&Vs[vrow][((((ks << 1) | lh) ^ (l32 & 7)) << 3)];
          o_acc[nt] = MFMA32(pf[ks], vf, o_acc[nt]);
        }
      }
    }

    // ---- epilogue: normalize + store ----
    fp32x16 inv;
#pragma unroll
    for (int r = 0; r < 16; ++r)
      inv[r] = (l_acc[r] > 0.f) ? 1.f / l_acc[r] : 0.f;
#pragma unroll
    for (int nt = 0; nt < 2; ++nt)
#pragma unroll
      for (int r = 0; r < 16; ++r) {
        const int t = t0 + 4 * lh + (r & 3) + 8 * (r >> 2);
        Obuf[(size_t)(b * Tq + t) * 2048 + qh * Hq + sh * 64 + nt * 32 + l32] =
            f2b(o_acc[nt][r] * inv[r]);
      }
  }
}

// ---------------- launcher --------------------------------------------------

extern "C" void kernel_launch(void* const* d_in, const int* in_sizes, int n_in,
                              void* d_out, int out_size, void* d_ws, size_t ws_size,
                              hipStream_t stream) {
  const float* x = (const float*)d_in[0];
  const int* seg = (const int*)d_in[1];
  const float* wq = (const float*)d_in[2];
  const float* wk = (const float*)d_in[3];
  const float* wv = (const float*)d_in[4];
  const float* wo = (const float*)d_in[5];
  const float* q_scale = (const float*)d_in[6];
  const float* k_scale = (const float*)d_in[7];
  float* out = (float*)d_out;

  char* ws = (char*)d_ws;
  u16* xb = (u16*)(ws);                              //  8 MB: x bf16 (4096x1024)
  u16* wqkv_t = (u16*)(ws + 8388608);                //  8 MB: fused B^T (4096x1024)
  u16* qkv = (u16*)(ws + 16777216);                  // 32 MB: q|k (v region unused)
  u16* vt = (u16*)(ws + 50331648);                   //  8 MB: v^T (2,8,128,2048)
  u16* wo_t = (u16*)(ws + 58720256);                 //  4 MB: wo^T (1024x2048)
  u16* Obuf = (u16*)(ws + 62914560);                 // 16 MB: attn out (4096x2048)
  int* posb = (int*)(ws + 79691776);                 // 16 KB: positions

  prep_kernel<<<10242, 256, 0, stream>>>(x, wq, wk, wv, wo, seg,
                                         xb, wqkv_t, wo_t, posb);

  gemm_qkv_kernel<<<dim3(32, 32, 1), 256, 0, stream>>>(
      xb, wqkv_t, qkv, vt, posb, q_scale, k_scale);

  flash_kernel<<<512, 256, 0, stream>>>(qkv, vt, posb, seg, Obuf);

  gemm_out_kernel<<<dim3(16, 32, 1), 256, 0, stream>>>(Obuf, wo_t, out);
}